// Round 12
// baseline (85.309 us; speedup 1.0000x reference)
//
#include <hip/hip_runtime.h>

typedef __attribute__((ext_vector_type(8))) __bf16 bf16x8;
typedef __attribute__((ext_vector_type(4))) float f32x4;

#define NB 8
#define NN 2048
#define NF 256
#define NU 256

static __device__ __forceinline__ unsigned short f2bf(float f) {
    union { float f; unsigned u; } a; a.f = f;
    unsigned r = a.u + 0x7FFFu + ((a.u >> 16) & 1u);   // RNE, no NaN inputs
    return (unsigned short)(r >> 16);
}

// hardware async global->LDS, 16B/lane
static __device__ __forceinline__ void glds16(const void* g, void* l) {
    __builtin_amdgcn_global_load_lds(
        (const __attribute__((address_space(1))) void*)g,
        (__attribute__((address_space(3))) void*)l, 16, 0, 0);
}

// ---------------- kernel 0: W -> MFMA B-fragment layout (bf16) ---------------
// WTf[z][kc][ub][lane][e] = W_z[kc*32 + (lane>>4)*8 + e][ub*16 + (lane&15)]
__global__ __launch_bounds__(256) void wfrag_kernel(
    const float* __restrict__ Wm, const float* __restrict__ Wu,
    unsigned short* __restrict__ WTf) {
    int idx = blockIdx.x * 256 + threadIdx.x;   // 16384 total
    int l  = idx & 63;
    int ub = (idx >> 6) & 15;
    int kc = (idx >> 10) & 7;
    int z  = idx >> 13;
    const float* W = z ? Wu : Wm;
    int u  = ub * 16 + (l & 15);
    int k0 = kc * 32 + (l >> 4) * 8;
    unsigned short p[8];
#pragma unroll
    for (int e = 0; e < 8; ++e) p[e] = f2bf(W[(k0 + e) * NU + u]);
    uint4 v;
    v.x = (unsigned)p[0] | ((unsigned)p[1] << 16);
    v.y = (unsigned)p[2] | ((unsigned)p[3] << 16);
    v.z = (unsigned)p[4] | ((unsigned)p[5] << 16);
    v.w = (unsigned)p[6] | ((unsigned)p[7] << 16);
    *(uint4*)(WTf + (size_t)idx * 8) = v;
}

// ---------------- kernel 1: h = bf16(x @ W_msg), stored in B-frag order ------
// Hf[b][ib][ub][lane][e] = h[b][ib*32 + (lane>>4)*8 + e][ub*16 + (lane&15)]
__global__ __launch_bounds__(256) void h_kernel(
    const float* __restrict__ x, const unsigned short* __restrict__ WTf,
    unsigned short* __restrict__ Hf) {
    int t = threadIdx.x;
    int w = t >> 6, l = t & 63;
    int l15 = l & 15, lh = l >> 4;
    int m0 = blockIdx.x * 64 + w * 16;
    const f32x4 fz = {0.f, 0.f, 0.f, 0.f};
    f32x4 acc[16];
#pragma unroll
    for (int i = 0; i < 16; ++i) acc[i] = fz;
    const float* xrow = x + (size_t)(m0 + l15) * NF;
#pragma unroll
    for (int kc = 0; kc < 8; ++kc) {
        int k0 = kc * 32 + lh * 8;
        float4 xa = *(const float4*)(xrow + k0);
        float4 xb = *(const float4*)(xrow + k0 + 4);
        union { unsigned short s[8]; bf16x8 v; } af;
        af.s[0] = f2bf(xa.x); af.s[1] = f2bf(xa.y);
        af.s[2] = f2bf(xa.z); af.s[3] = f2bf(xa.w);
        af.s[4] = f2bf(xb.x); af.s[5] = f2bf(xb.y);
        af.s[6] = f2bf(xb.z); af.s[7] = f2bf(xb.w);
#pragma unroll
        for (int ub = 0; ub < 16; ++ub) {
            union { uint4 q; bf16x8 v; } bf;
            bf.q = *(const uint4*)(WTf + (size_t)(kc * 1024 + ub * 64 + l) * 8);
            acc[ub] = __builtin_amdgcn_mfma_f32_16x16x32_bf16(af.v, bf.v, acc[ub], 0, 0, 0);
        }
    }
    int bb = m0 >> 11;
    int n0 = m0 & (NN - 1);
    int ib = n0 >> 5;
    int kl = ((n0 & 31) >> 3) + (lh >> 1);
    int e0 = (lh & 1) * 4;
#pragma unroll
    for (int ub = 0; ub < 16; ++ub) {
        unsigned short p[4];
#pragma unroll
        for (int r = 0; r < 4; ++r) p[r] = f2bf(acc[ub][r]);
        size_t off = ((size_t)((bb * 64 + ib) * 16 + ub)) * 512 + (size_t)(kl * 16 + l15) * 8 + e0;
        uint2 v;
        v.x = (unsigned)p[0] | ((unsigned)p[1] << 16);
        v.y = (unsigned)p[2] | ((unsigned)p[3] << 16);
        *(uint2*)(Hf + off) = v;
    }
}

// ---------------- kernel 2: msg GEMM + mean + fused upd GEMM + relu ----------
// m97-faithful: 512 blocks (b=blk&7, jt=32, ut=2) x 512 thr (8 waves: wj2 x wu4,
// wave = j32 x u32). Chunk K=64: 64 MFMAs per block per barrier-pair.
// glds-staged int tile + Hf tile (contiguous), in-LDS transpose, plain
// __syncthreads, no asm, compiler-scheduled. 74 KB LDS -> 2 blocks/CU.
#define SWZA(j) (((j) & 7) << 4)

__global__ __launch_bounds__(512) void msg_kernel(
    const int* __restrict__ adj, const unsigned short* __restrict__ Hf,
    const float* __restrict__ x, const unsigned short* __restrict__ WTf,
    const float* __restrict__ bias, float* __restrict__ out) {
    __shared__ int Ibuf[2][64 * 64];            // 2 x 16KB raw adj ints [i][j]
    __shared__ unsigned short Afr[64 * 64];     // 8KB bf16 A-frags [j][i], swizzled
    __shared__ unsigned short Bbuf[2][16 * 512];// 2 x 16KB Hf frags (16 slots)
    __shared__ int degs[512];
    __shared__ float rdeg[64];

    int blk = blockIdx.x;
    int b = blk & 7, jt = (blk >> 3) & 31, ut = blk >> 8;
    int j0 = jt * 64;
    int t = threadIdx.x;
    int w = t >> 6, l = t & 63;
    int wj = w & 1, wu = w >> 1;                // wj: j-half32, wu: u-quarter32
    int l15 = l & 15, lh = l >> 4;
    int jT = t & 63, i0T = (t >> 6) * 8;        // transpose map: col jT, rows i0T..+7

    const f32x4 fz = {0.f, 0.f, 0.f, 0.f};
    f32x4 acc[2][2];                            // [jf][ub]
#pragma unroll
    for (int a = 0; a < 2; ++a)
#pragma unroll
        for (int c = 0; c < 2; ++c) acc[a][c] = fz;

    // glds sources. ints op k: rows (w*2+k)*4 + (l>>4), cols j0 + (l&15)*4
    const int* asrc = adj + (size_t)b * NN * NN + (size_t)(w * 8 + (l >> 4) * 2) * NN
                      + j0 + (l & 15) * 4;      // note: rows for k via +4*NN... see below
    // careful: op k adds 4 rows -> recompute cleanly:
    const int* asrc0 = adj + (size_t)b * NN * NN
                       + (size_t)((w * 2 + 0) * 4 + (l >> 4)) * NN + j0 + (l & 15) * 4;
    const int* asrc1 = adj + (size_t)b * NN * NN
                       + (size_t)((w * 2 + 1) * 4 + (l >> 4)) * NN + j0 + (l & 15) * 4;
    // Hf op k: slot g2 = w*2+k; kk = g2>>3; g = g2&7; src advances 16384 shorts/chunk
    int g20 = w * 2, g21 = w * 2 + 1;
    const unsigned short* hsrc0 = Hf + ((size_t)(b * 64 + (g20 >> 3)) * 16
                                        + ut * 8 + (g20 & 7)) * 512 + (size_t)l * 8;
    const unsigned short* hsrc1 = Hf + ((size_t)(b * 64 + (g21 >> 3)) * 16
                                        + ut * 8 + (g21 & 7)) * 512 + (size_t)l * 8;
    // LDS dests (per-lane = base + l*16)
    char* idst0 = (char*)(&Ibuf[0][0]) + (w * 2 + 0) * 1024 + l * 16;
    char* idst1 = (char*)(&Ibuf[0][0]) + (w * 2 + 1) * 1024 + l * 16;
    char* bdst0 = (char*)(&Bbuf[0][0]) + g20 * 1024 + l * 16;
    char* bdst1 = (char*)(&Bbuf[0][0]) + g21 * 1024 + l * 16;

    int dsum = 0;

    auto STAGE = [&](int c, int bufsel) {
        size_t arow = (size_t)c * 64 * NN;
        size_t hoff = (size_t)c * 16384;
        int boff = bufsel * 16384;              // bytes: Ibuf/Bbuf buffers are 16KB
        glds16(asrc0 + arow, idst0 + boff);
        glds16(asrc1 + arow, idst1 + boff);
        glds16(hsrc0 + hoff, bdst0 + boff);
        glds16(hsrc1 + hoff, bdst1 + boff);
    };

    // prologue: chunk 0 -> buf 0
    STAGE(0, 0);
    __syncthreads();

#pragma unroll 1
    for (int c = 0; c < 32; ++c) {
        int cur = c & 1;
        if (c < 31) STAGE(c + 1, cur ^ 1);

        // transpose chunk c: col jT, rows i0T..i0T+7 -> one swizzled b128 write
        {
            const int* ird = &Ibuf[cur][0];
            int r0 = ird[(i0T + 0) * 64 + jT];
            int r1 = ird[(i0T + 1) * 64 + jT];
            int r2 = ird[(i0T + 2) * 64 + jT];
            int r3 = ird[(i0T + 3) * 64 + jT];
            int r4 = ird[(i0T + 4) * 64 + jT];
            int r5 = ird[(i0T + 5) * 64 + jT];
            int r6 = ird[(i0T + 6) * 64 + jT];
            int r7 = ird[(i0T + 7) * 64 + jT];
            dsum += r0 + r1 + r2 + r3 + r4 + r5 + r6 + r7;
            uint4 pk;
            pk.x = ((unsigned)(r0 | (r1 << 16))) * 0x3F80u;
            pk.y = ((unsigned)(r2 | (r3 << 16))) * 0x3F80u;
            pk.z = ((unsigned)(r4 | (r5 << 16))) * 0x3F80u;
            pk.w = ((unsigned)(r6 | (r7 << 16))) * 0x3F80u;
            *(uint4*)((char*)Afr + jT * 128 + ((i0T * 2) ^ SWZA(jT))) = pk;
        }

        __syncthreads();   // Afr visible; staged chunk c+1 drained (m97-style)

        // MFMA chunk c: 8 per wave, 64 per block
        {
            bf16x8 af[2][2];
#pragma unroll
            for (int jf = 0; jf < 2; ++jf) {
                int j = wj * 32 + jf * 16 + l15;
#pragma unroll
                for (int kk = 0; kk < 2; ++kk)
                    af[jf][kk] = *(const bf16x8*)((const char*)Afr + j * 128 +
                                    ((kk * 64 + lh * 16) ^ SWZA(j)));
            }
#pragma unroll
            for (int kk = 0; kk < 2; ++kk)
#pragma unroll
                for (int ub = 0; ub < 2; ++ub) {
                    union { uint4 q; bf16x8 v; } bq;
                    bq.q = *(const uint4*)((const char*)(&Bbuf[cur][0]) +
                             (kk * 8 + wu * 2 + ub) * 1024 + l * 16);
#pragma unroll
                    for (int jf = 0; jf < 2; ++jf)
                        acc[jf][ub] = __builtin_amdgcn_mfma_f32_16x16x32_bf16(
                            af[jf][kk], bq.v, acc[jf][ub], 0, 0, 0);
                }
        }

        __syncthreads();   // all reads of [cur] done before it is restaged
    }

    // degree reduce: thread t covered col jT, rows i0T..+7 of every chunk
    degs[t] = dsum;
    __syncthreads();
    if (t < 64) {
        int d = 0;
#pragma unroll
        for (int g = 0; g < 8; ++g) d += degs[g * 64 + t];
        rdeg[t] = d > 0 ? 1.0f / (float)d : 0.0f;
    }
    __syncthreads();

    // scale msg accumulator by 1/deg (TF segment-mean: deg==0 -> 0)
#pragma unroll
    for (int jf = 0; jf < 2; ++jf)
#pragma unroll
        for (int rr = 0; rr < 4; ++rr) {
            float sc = rdeg[wj * 32 + jf * 16 + lh * 4 + rr];
#pragma unroll
            for (int ub = 0; ub < 2; ++ub) acc[jf][ub][rr] *= sc;
        }

    // fused upd GEMM: acc += bf16(x_rows) @ W_upd
    const float* xb = x + ((size_t)b * NN + j0) * NF;
#pragma unroll
    for (int kc = 0; kc < 8; ++kc) {
        int k0 = kc * 32 + lh * 8;
        bf16x8 xf[2];
#pragma unroll
        for (int jf = 0; jf < 2; ++jf) {
            const float* xr = xb + (size_t)(wj * 32 + jf * 16 + l15) * NF + k0;
            float4 xa = *(const float4*)xr;
            float4 xc = *(const float4*)(xr + 4);
            union { unsigned short sh[8]; bf16x8 v; } a2;
            a2.sh[0] = f2bf(xa.x); a2.sh[1] = f2bf(xa.y);
            a2.sh[2] = f2bf(xa.z); a2.sh[3] = f2bf(xa.w);
            a2.sh[4] = f2bf(xc.x); a2.sh[5] = f2bf(xc.y);
            a2.sh[6] = f2bf(xc.z); a2.sh[7] = f2bf(xc.w);
            xf[jf] = a2.v;
        }
#pragma unroll
        for (int ub = 0; ub < 2; ++ub) {
            int ubg = ut * 8 + wu * 2 + ub;
            union { uint4 q; bf16x8 v; } bf;
            bf.q = *(const uint4*)(WTf + (size_t)(8192 + kc * 1024 + ubg * 64 + l) * 8);
#pragma unroll
            for (int jf = 0; jf < 2; ++jf)
                acc[jf][ub] = __builtin_amdgcn_mfma_f32_16x16x32_bf16(
                    xf[jf], bf.v, acc[jf][ub], 0, 0, 0);
        }
    }

    // epilogue: + bias, relu, store
    float* ob = out + ((size_t)b * NN + j0) * NU;
#pragma unroll
    for (int jf = 0; jf < 2; ++jf)
#pragma unroll
        for (int ub = 0; ub < 2; ++ub) {
            int u = ut * 128 + (wu * 2 + ub) * 16 + l15;
            float bv = bias[u];
#pragma unroll
            for (int rr = 0; rr < 4; ++rr) {
                float v = acc[jf][ub][rr] + bv;
                ob[(size_t)(wj * 32 + jf * 16 + lh * 4 + rr) * NU + u] = fmaxf(v, 0.f);
            }
        }
}

extern "C" void kernel_launch(void* const* d_in, const int* in_sizes, int n_in,
                              void* d_out, int out_size, void* d_ws, size_t ws_size,
                              hipStream_t stream) {
    const float* x    = (const float*)d_in[0];
    const int*   adj  = (const int*)d_in[1];
    const float* Wm   = (const float*)d_in[2];
    const float* Wu   = (const float*)d_in[3];
    const float* bias = (const float*)d_in[4];
    float* out = (float*)d_out;

    char* ws = (char*)d_ws;
    unsigned short* WTf = (unsigned short*)(ws);                 // 256 KiB
    unsigned short* Hf  = (unsigned short*)(ws + (1ull << 20));  // 8 MiB @ 1M

    wfrag_kernel<<<64, 256, 0, stream>>>(Wm, Wu, WTf);
    h_kernel<<<256, 256, 0, stream>>>(x, WTf, Hf);
    msg_kernel<<<512, 512, 0, stream>>>(adj, Hf, x, WTf, bias, out);
}